// Round 1
// baseline (517.965 us; speedup 1.0000x reference)
//
#include <hip/hip_runtime.h>
#include <stdint.h>

#define NB 8
#define NA 100000
#define NC 80
#define NM 50
#define NH 512
#define NW 512

// ws layout (floats): [0..7]=cls_sum  [8..15]=xy_sum  [16..23]=ang_sum  [24..31]=npos
//                     [32] (as int) = states-layout flag (bit0: 1-byte elements)

__global__ void detect_states_layout(const uint32_t* __restrict__ w, int* __restrict__ flag) {
    // Scan first 64K words (256 KB; smallest possible states buffer is 2 MB).
    // Packed-uint8 bools -> words whose bytes are all in {0,1} with value > 1.
    // int32 bools (0/1) and fp32 bools (0x3F800000) never match.
    uint32_t ev = 0;
    for (int j = threadIdx.x; j < 65536; j += 256) {
        uint32_t v = w[j];
        if (((v & 0xFEFEFEFEu) == 0u) && (v > 1u)) ev = 1u;
    }
    if (ev) atomicOr(flag, 1);
}

__global__ __launch_bounds__(256) void focal_main(
    const float* __restrict__ cls,   // (B, A, C)
    const float* __restrict__ reg,   // (B, A, 3)
    const float* __restrict__ anch,  // (1, A, 3)
    const float* __restrict__ ann,   // (B, M, 4)
    const void*  __restrict__ states,// (B, 1, H, W) bool (layout per flag)
    const int*   __restrict__ flag,
    float* __restrict__ acc)
{
    __shared__ float4 sann[NM];
    __shared__ int    scode[256];
    __shared__ float  sdamp[256];
    __shared__ float  sred[4];   // [0]=npos [1]=xy [2]=ang [3]=cls

    const int t  = threadIdx.x;
    const int b  = blockIdx.y;
    const int i0 = blockIdx.x * 256;
    const int i  = i0 + t;

    if (t < NM) sann[t] = ((const float4*)(ann + (size_t)b * NM * 4))[t];
    if (t < 4)  sred[t] = 0.0f;
    __syncthreads();

    // ---- Phase A: per-anchor assignment + regression losses ----
    int   code = -2;     // -2 = ignore, -1 = neg, >=0 = pos class
    float damp = 1.0f;
    bool  pos  = false;
    float xyc = 0.0f, angc = 0.0f;

    if (i < NA) {
        const float ax  = anch[3 * i + 0];
        const float ay  = anch[3 * i + 1];
        const float aal = anch[3 * i + 2];

        float d2min = 1e30f;
        int   mmin  = 0;
        #pragma unroll 10
        for (int m = 0; m < NM; ++m) {
            float4 a4 = sann[m];
            float dx = ax - a4.x, dy = ay - a4.y;
            float d2 = dx * dx + dy * dy;
            if (d2 < d2min) { d2min = d2; mmin = m; }
        }
        float4 am  = sann[mmin];
        float dxy  = sqrtf(d2min);
        float dal  = fabsf(aal - am.z);
        pos = (dxy <= 5.0f) && (dal <= 10.0f);
        bool neg = (dxy >= 7.5f) || (dal >= 15.0f);
        code = pos ? (int)am.w : (neg ? -1 : -2);

        const int ix = (int)rintf(ax);   // jnp.round = half-to-even = rintf
        const int iy = (int)rintf(ay);
        const size_t sidx = (size_t)b * NH * NW + (size_t)iy * NW + ix;
        bool gt;
        if (*flag & 1) gt = ((const uint8_t*)states)[sidx] != 0;
        else           gt = ((const uint32_t*)states)[sidx] != 0u;
        damp = gt ? 1.0f : 0.1f;

        if (pos) {
            const float* r = reg + ((size_t)b * NA + i) * 3;
            const float r0 = r[0], r1 = r[1], r2 = r[2];
            const float tdx = am.x - ax, tdy = am.y - ay, tda = am.z - aal;
            const float dxr = fabsf(tdx - r0);
            const float dyr = fabsf(tdy - r1);
            const float lx = (dxr <= (1.0f / 9.0f)) ? 4.5f * dxr * dxr : dxr - (0.5f / 9.0f);
            const float ly = (dyr <= (1.0f / 9.0f)) ? 4.5f * dyr * dyr : dyr - (0.5f / 9.0f);
            xyc  = (lx + ly) * damp;
            angc = fmaxf((fabsf(tda - r2) - 10.0f) / 5.0f, 0.0f) * damp;
        }
    }
    scode[t] = code;
    sdamp[t] = damp;
    if (pos) {
        atomicAdd(&sred[0], 1.0f);
        atomicAdd(&sred[1], xyc);
        atomicAdd(&sred[2], angc);
    }
    __syncthreads();

    // ---- Phase B: streamed focal loss over this block's (256 x 80) chunk ----
    const int nA = min(256, NA - i0);
    const float4* cbase = (const float4*)(cls + ((size_t)b * NA + i0) * NC);
    const int n4 = nA * (NC / 4);   // float4s in this chunk (C=80 -> 20 per anchor)

    float csum = 0.0f;
    for (int j = t; j < n4; j += 256) {
        const int   la = j / 20;          // float4 never crosses an anchor (80 % 4 == 0)
        const int   cb = (j % 20) * 4;
        const int   c  = scode[la];
        if (c == -2) continue;
        const float dmp = sdamp[la];
        const float4 v = cbase[j];

        float s = 0.0f;
        {
            float p = fminf(fmaxf(v.x, 1e-4f), 0.9999f);
            s += (cb + 0 == c) ? 0.95f * (1.0f - p) * (1.0f - p) * (-__logf(p))
                               : 0.05f * p * p * (-__logf(1.0f - p));
        }
        {
            float p = fminf(fmaxf(v.y, 1e-4f), 0.9999f);
            s += (cb + 1 == c) ? 0.95f * (1.0f - p) * (1.0f - p) * (-__logf(p))
                               : 0.05f * p * p * (-__logf(1.0f - p));
        }
        {
            float p = fminf(fmaxf(v.z, 1e-4f), 0.9999f);
            s += (cb + 2 == c) ? 0.95f * (1.0f - p) * (1.0f - p) * (-__logf(p))
                               : 0.05f * p * p * (-__logf(1.0f - p));
        }
        {
            float p = fminf(fmaxf(v.w, 1e-4f), 0.9999f);
            s += (cb + 3 == c) ? 0.95f * (1.0f - p) * (1.0f - p) * (-__logf(p))
                               : 0.05f * p * p * (-__logf(1.0f - p));
        }
        csum += s * dmp;
    }
    atomicAdd(&sred[3], csum);
    __syncthreads();

    if (t == 0) {
        atomicAdd(&acc[b],      sred[3]);  // cls_sum
        atomicAdd(&acc[8 + b],  sred[1]);  // xy_sum
        atomicAdd(&acc[16 + b], sred[2]);  // ang_sum
        atomicAdd(&acc[24 + b], sred[0]);  // npos
    }
}

__global__ void focal_final(const float* __restrict__ acc, float* __restrict__ out) {
    if (threadIdx.x == 0) {
        float c = 0.0f, x = 0.0f, a = 0.0f;
        for (int b = 0; b < NB; ++b) {
            float np = acc[24 + b];
            c += acc[b] / fmaxf(np, 1.0f);
            if (np > 0.0f) {
                x += acc[8 + b]  / (2.0f * np);
                a += acc[16 + b] / np;
            }
        }
        out[0] = c / (float)NB;
        out[1] = x / (float)NB;
        out[2] = a / (float)NB;
    }
}

extern "C" void kernel_launch(void* const* d_in, const int* in_sizes, int n_in,
                              void* d_out, int out_size, void* d_ws, size_t ws_size,
                              hipStream_t stream) {
    const float* cls    = (const float*)d_in[0];
    const float* reg    = (const float*)d_in[1];
    const float* anch   = (const float*)d_in[2];
    const float* ann    = (const float*)d_in[3];
    const void*  states = d_in[4];

    float* acc = (float*)d_ws;
    int*   flag = (int*)((float*)d_ws + 32);

    hipMemsetAsync(d_ws, 0, 256, stream);
    detect_states_layout<<<1, 256, 0, stream>>>((const uint32_t*)states, flag);

    dim3 grid((NA + 255) / 256, NB);
    focal_main<<<grid, 256, 0, stream>>>(cls, reg, anch, ann, states, flag, acc);

    focal_final<<<1, 64, 0, stream>>>(acc, (float*)d_out);
}